// Round 1
// baseline (444.159 us; speedup 1.0000x reference)
//
#include <hip/hip_runtime.h>

typedef unsigned short u16;
typedef __bf16 bf16x8 __attribute__((ext_vector_type(8)));
typedef float  f32x16 __attribute__((ext_vector_type(16)));

#define NB 4
#define NN 4096
#define ND 256

__device__ __forceinline__ u16 f2bf(float x) {
    return __builtin_bit_cast(u16, (__bf16)x);
}

// ---------------- kernel A: bulk f32 -> bf16 convert of val ----------------
__global__ void k_cvt_val(const float* __restrict__ val, u16* __restrict__ val_bf) {
    int i = blockIdx.x * blockDim.x + threadIdx.x;   // exactly NB*NN*ND/4 threads
    const float4 v = ((const float4*)val)[i];
    ushort4 o;
    o.x = f2bf(v.x); o.y = f2bf(v.y); o.z = f2bf(v.z); o.w = f2bf(v.w);
    ((ushort4*)val_bf)[i] = o;
}

// ---------------- kernel A2: Wv -> WvT (bf16) ----------------
__global__ void k_cvt_wvT(const float* __restrict__ Wv, u16* __restrict__ wvT) {
    int i = blockIdx.x * blockDim.x + threadIdx.x;   // ND*ND threads
    int e = i >> 8, d = i & 255;
    wvT[i] = f2bf(Wv[d * 256 + e]);   // wvT[e][d] = Wv[d][e]
}

// Stage a 64x256 bf16 tile (row stride 256) global->LDS with chunk swizzle.
// Chunk = 8 bf16 = 16B. Swizzled chunk pos p = (c & ~7) | ((c+row) & 7).
__device__ __forceinline__ void stage_tile_64x256(u16* lds, const u16* __restrict__ src, int tid) {
    #pragma unroll
    for (int k = 0; k < 8; k++) {
        int idx = k * 256 + tid;
        int row = idx >> 5, c = idx & 31;
        uint4 v = *(const uint4*)(src + row * 256 + c * 8);
        int p = (c & ~7) | ((c + row) & 7);
        *(uint4*)(lds + row * 256 + p * 8) = v;
    }
}

__device__ __forceinline__ bf16x8 ld_frag(const u16* lds, int row, int chunksPerRow, int c) {
    int p = (c & ~7) | ((c + row) & 7);
    return *(const bf16x8*)(lds + (row * chunksPerRow + p) * 8);
}

// ---------------- kernel B: pv = val @ Wv, written transposed vT[b][e][n] (bf16) ----------------
__global__ __launch_bounds__(256) void k_pv_gemm(const u16* __restrict__ val_bf,
                                                 const u16* __restrict__ wvT,
                                                 u16* __restrict__ vT_bf) {
    __shared__ u16 ldsA[64 * 256];
    int tid = threadIdx.x;
    int wave = tid >> 6, lane = tid & 63;
    int h = lane >> 5, l31 = lane & 31;
    int r0 = blockIdx.x * 64;                       // flat row over NB*NN

    stage_tile_64x256(ldsA, val_bf + (size_t)r0 * 256, tid);
    __syncthreads();

    int arow = (wave >> 1) * 32 + l31;
    f32x16 acc[4] = {};
    #pragma unroll
    for (int s = 0; s < 16; s++) {
        bf16x8 af = ld_frag(ldsA, arow, 32, 2 * s + h);
        #pragma unroll
        for (int t = 0; t < 4; t++) {
            int e = (wave & 1) * 128 + t * 32 + l31;
            bf16x8 bfr = *(const bf16x8*)(wvT + e * 256 + s * 16 + h * 8);
            acc[t] = __builtin_amdgcn_mfma_f32_32x32x16_bf16(af, bfr, acc[t], 0, 0, 0);
        }
    }
    int b = r0 >> 12;
    int n0 = r0 & 4095;
    #pragma unroll
    for (int t = 0; t < 4; t++) {
        int e = (wave & 1) * 128 + t * 32 + l31;
        #pragma unroll
        for (int r = 0; r < 16; r++) {
            int n = n0 + (wave >> 1) * 32 + (r & 3) + 8 * (r >> 2) + 4 * h;
            vT_bf[((size_t)(b * 256 + e)) * 4096 + n] = f2bf(acc[t][r]);
        }
    }
}

// ---------------- kernel C: flash-style softsign propagation ----------------
__global__ __launch_bounds__(256) void k_main(const u16* __restrict__ val_bf,
                                              const u16* __restrict__ vT_bf,
                                              const float* __restrict__ state,
                                              float* __restrict__ ds_out,
                                              float* __restrict__ dval_out) {
    __shared__ u16 ldsK[64 * 256];   // K-tile (also Q staging), [row][d], swizzled
    __shared__ u16 ldsV[256 * 64];   // Vt-tile [e][m-local], swizzled
    __shared__ u16 ldsP[64 * 64];    // P-tile [row][m-local], swizzled
    __shared__ float dsbuf[64];

    int tid = threadIdx.x;
    int wave = tid >> 6, lane = tid & 63;
    int h = lane >> 5, l31 = lane & 31;

    // XCD-aware remap: keep one batch's working set on 2 XCDs (perf only; bijective)
    int id = blockIdx.x;
    int xcd = id & 7;
    int bb = xcd >> 1;
    int rowblk = (id >> 3) * 2 + (xcd & 1);
    int row0 = rowblk * 64;

    if (tid < 64) dsbuf[tid] = 0.0f;

    // Phase 0: stage Q into ldsK, pull Q fragments to registers
    stage_tile_64x256(ldsK, val_bf + (size_t)(bb * 4096 + row0) * 256, tid);
    __syncthreads();
    bf16x8 qf[16];
    int qrow = (wave >> 1) * 32 + l31;
    #pragma unroll
    for (int s = 0; s < 16; s++) qf[s] = ld_frag(ldsK, qrow, 32, 2 * s + h);
    __syncthreads();

    f32x16 oacc[4] = {};
    float dsacc[16] = {};
    int mrow = (wave & 1) * 32 + l31;   // K-tile row (S column index)
    int prow = (wave >> 1) * 32 + l31;  // P row (O row index)

    for (int mt = 0; mt < 64; mt++) {
        int m0 = mt * 64;
        // stage K-tile
        stage_tile_64x256(ldsK, val_bf + (size_t)(bb * 4096 + m0) * 256, tid);
        // stage Vt-tile: 256 rows (e) x 64 cols (m-local)
        #pragma unroll
        for (int k = 0; k < 8; k++) {
            int idx = k * 256 + tid;
            int e = idx >> 3, c = idx & 7;
            uint4 v = *(const uint4*)(vT_bf + ((size_t)(bb * 256 + e)) * 4096 + m0 + c * 8);
            int p = (c + e) & 7;
            *(uint4*)(ldsV + e * 64 + p * 8) = v;
        }
        __syncthreads();

        // S = Q x K^T (one 32x32 tile per wave)
        f32x16 sacc = {};
        #pragma unroll
        for (int s = 0; s < 16; s++) {
            bf16x8 kf = ld_frag(ldsK, mrow, 32, 2 * s + h);
            sacc = __builtin_amdgcn_mfma_f32_32x32x16_bf16(qf[s], kf, sacc, 0, 0, 0);
        }

        // softsign, ds partial accumulate, P -> LDS (C-layout -> A-layout via LDS)
        float sv = state[bb * 4096 + m0 + (wave & 1) * 32 + l31];
        #pragma unroll
        for (int r = 0; r < 16; r++) {
            float s = sacc[r];
            float pval = s / (1.0f + fabsf(s));
            dsacc[r] += pval * sv;
            int pr = (wave >> 1) * 32 + (r & 3) + 8 * (r >> 2) + 4 * h;
            int pc = (wave & 1) * 32 + l31;
            int cc = pc >> 3;
            int pp = (cc + pr) & 7;
            ldsP[pr * 64 + pp * 8 + (pc & 7)] = f2bf(pval);
        }
        __syncthreads();

        // O += P x Vt  (wave: rows 32*(w>>1), cols 128*(w&1)..+127)
        #pragma unroll
        for (int s = 0; s < 4; s++) {
            bf16x8 pf = ld_frag(ldsP, prow, 8, 2 * s + h);
            #pragma unroll
            for (int t = 0; t < 4; t++) {
                int e = (wave & 1) * 128 + t * 32 + l31;
                bf16x8 vf = ld_frag(ldsV, e, 8, 2 * s + h);
                oacc[t] = __builtin_amdgcn_mfma_f32_32x32x16_bf16(pf, vf, oacc[t], 0, 0, 0);
            }
        }
        __syncthreads();   // protect ldsK/ldsV/ldsP before next stage
    }

    // write delta_val (f32, coalesced across l31)
    #pragma unroll
    for (int t = 0; t < 4; t++) {
        int col = (wave & 1) * 128 + t * 32 + l31;
        #pragma unroll
        for (int r = 0; r < 16; r++) {
            int row = (wave >> 1) * 32 + (r & 3) + 8 * (r >> 2) + 4 * h;
            dval_out[(size_t)(bb * 4096 + row0 + row) * 256 + col] = oacc[t][r];
        }
    }

    // delta_state: reduce dsacc over the 32-lane column group, combine waves via LDS
    #pragma unroll
    for (int m = 1; m <= 16; m <<= 1) {
        #pragma unroll
        for (int r = 0; r < 16; r++) dsacc[r] += __shfl_xor(dsacc[r], m);
    }
    if (l31 == 0) {
        #pragma unroll
        for (int r = 0; r < 16; r++) {
            int row = (wave >> 1) * 32 + (r & 3) + 8 * (r >> 2) + 4 * h;
            atomicAdd(&dsbuf[row], dsacc[r]);
        }
    }
    __syncthreads();
    if (tid < 64) ds_out[bb * 4096 + row0 + tid] = dsbuf[tid];
}

extern "C" void kernel_launch(void* const* d_in, const int* in_sizes, int n_in,
                              void* d_out, int out_size, void* d_ws, size_t ws_size,
                              hipStream_t stream) {
    const float* val   = (const float*)d_in[0];   // [B,N,D] f32
    const float* state = (const float*)d_in[1];   // [B,N]   f32
    const float* Wv    = (const float*)d_in[2];   // [D,D]   f32

    float* ds_out   = (float*)d_out;              // [B,N]
    float* dval_out = ds_out + NB * NN;           // [B,N,D]

    u16* val_bf = (u16*)d_ws;                              // 8 MB  bf16 val
    u16* vT_bf  = val_bf + (size_t)NB * NN * ND;           // 8 MB  bf16 (val@Wv)^T per batch
    u16* wvT    = vT_bf  + (size_t)NB * NN * ND;           // 128KB bf16 Wv^T

    k_cvt_val<<<NB * NN * ND / 4 / 256, 256, 0, stream>>>(val, val_bf);
    k_cvt_wvT<<<ND * ND / 256, 256, 0, stream>>>(Wv, wvT);
    k_pv_gemm<<<NB * NN / 64, 256, 0, stream>>>(val_bf, wvT, vT_bf);
    k_main<<<256, 256, 0, stream>>>(val_bf, vT_bf, state, ds_out, dval_out);
}

// Round 2
// 345.921 us; speedup vs baseline: 1.2840x; 1.2840x over previous
//
#include <hip/hip_runtime.h>

typedef unsigned short u16;
typedef unsigned int u32;
typedef __bf16 bf16x8 __attribute__((ext_vector_type(8)));
typedef float  f32x16 __attribute__((ext_vector_type(16)));

#define NB 4
#define NN 4096
#define ND 256

__device__ __forceinline__ u16 f2bf(float x) { return __builtin_bit_cast(u16, (__bf16)x); }
__device__ __forceinline__ u32 pack2(float a, float b) {
    return (u32)f2bf(a) | ((u32)f2bf(b) << 16);
}

// ---- prep: val -> bf16, Wv -> Wv^T bf16, state -> bf16 (one kernel, 3 ranges) ----
__global__ void k_prep(const float* __restrict__ val, const float* __restrict__ state,
                       const float* __restrict__ Wv,
                       u16* __restrict__ val_bf, u16* __restrict__ wvT, u16* __restrict__ st_bf) {
    int idx = blockIdx.x * 256 + threadIdx.x;
    if (idx < 1048576) {                       // 4,194,304 f32 as float4
        float4 v = ((const float4*)val)[idx];
        ushort4 o; o.x = f2bf(v.x); o.y = f2bf(v.y); o.z = f2bf(v.z); o.w = f2bf(v.w);
        ((ushort4*)val_bf)[idx] = o;
    } else if (idx < 1048576 + 65536) {        // Wv transpose
        int j = idx - 1048576; int e = j >> 8, d = j & 255;
        wvT[j] = f2bf(Wv[d * 256 + e]);
    } else {                                   // state, 16384 elements
        int k = idx - (1048576 + 65536);
        if (k < 16384) st_bf[k] = f2bf(state[k]);
    }
}

// ---- pv: vT[b][e][q] = (val@Wv)^T via D = Wv^T x val^T; coalesced bf16 stores ----
__global__ __launch_bounds__(64) void k_pv(const u16* __restrict__ val_bf,
                                           const u16* __restrict__ wvT,
                                           u16* __restrict__ vT_bf) {
    int wid = blockIdx.x;                      // 1024 waves of 64
    int lane = threadIdx.x;
    int l31 = lane & 31, h = lane >> 5;
    int bb = wid >> 8, es = (wid >> 5) & 7, qb = wid & 31;   // batch, e-strip(32), q-block(128)
    const u16* abase = wvT + (es * 32 + l31) * 256 + h * 8;
    const u16* bbase = val_bf + ((size_t)(bb * 4096 + qb * 128 + l31)) * 256 + h * 8;
    f32x16 acc[4] = {};
    for (int s = 0; s < 16; s++) {
        bf16x8 af = *(const bf16x8*)(abase + s * 16);
        #pragma unroll
        for (int qt = 0; qt < 4; qt++) {
            bf16x8 bfr = *(const bf16x8*)(bbase + qt * 32 * 256 + s * 16);
            acc[qt] = __builtin_amdgcn_mfma_f32_32x32x16_bf16(af, bfr, acc[qt], 0, 0, 0);
        }
    }
    #pragma unroll
    for (int qt = 0; qt < 4; qt++)
        #pragma unroll
        for (int r = 0; r < 16; r++) {
            int e = es * 32 + (r & 3) + 8 * (r >> 2) + 4 * h;
            vT_bf[((size_t)(bb * 256 + e)) * 4096 + qb * 128 + qt * 32 + l31] = f2bf(acc[qt][r]);
        }
}

// ---- main: barrier-free flash softsign; wave = (strip, msplit); epilogue LDS reduce ----
__global__ __launch_bounds__(256, 2) void k_main(const u16* __restrict__ val_bf,
                                                 const u16* __restrict__ vT_bf,
                                                 const u16* __restrict__ st_bf,
                                                 float* __restrict__ ds_out,
                                                 float* __restrict__ dval_out) {
    __shared__ float red[2 * 32 * 256];   // 64 KB, epilogue only
    __shared__ float dsbuf[32];

    int tid = threadIdx.x;
    int wave = tid >> 6, lane = tid & 63;
    int l31 = lane & 31, h = lane >> 5;

    int id = blockIdx.x;                  // [0,512)
    int xcd = id & 7;
    int bb = xcd >> 1;                    // batch pinned to an XCD pair (L2 locality)
    int strip = (xcd & 1) * 64 + (id >> 3);
    int q0 = strip * 32;
    int m_base = wave * 1024;             // 4 waves = 4 m-splits, no inter-wave deps in loop

    if (tid < 32) dsbuf[tid] = 0.0f;

    // Q fragments, resident in registers (B-operand layout: n=lane&31, k=h*8+j)
    const u16* qbase = val_bf + ((size_t)(bb * 4096 + q0 + l31)) * 256 + h * 8;
    bf16x8 qf[16];
    #pragma unroll
    for (int s = 0; s < 16; s++) qf[s] = *(const bf16x8*)(qbase + s * 16);

    f32x16 oacc[8] = {};
    f32x16 dsa = {};

    const u16* kbase0 = val_bf + ((size_t)(bb * 4096 + m_base + l31)) * 256 + h * 8;
    const u16* vbase0 = vT_bf + ((size_t)(bb * 256 + l31)) * 4096 + m_base + h * 8;
    const u16* stb    = st_bf + bb * 4096 + m_base + h * 8;

    for (int mt = 0; mt < 32; mt++) {
        // S^T = K x Q^T : D[m_local][q_local], lane holds col q=l31 (== A-layout rows for PV)
        const u16* kb = kbase0 + (size_t)mt * 32 * 256;
        f32x16 sacc = {};
        #pragma unroll
        for (int s = 0; s < 16; s++) {
            bf16x8 kf = *(const bf16x8*)(kb + s * 16);
            sacc = __builtin_amdgcn_mfma_f32_32x32x16_bf16(kf, qf[s], sacc, 0, 0, 0);
        }
        // softsign + pack to bf16 pairs; quads: Qi = regs [4i,4i+4) -> m = 8i + 4h + 0..3
        u32 c[8];
        #pragma unroll
        for (int i = 0; i < 8; i++) {
            float a = sacc[2 * i], b = sacc[2 * i + 1];
            a = a / (1.0f + fabsf(a));
            b = b / (1.0f + fabsf(b));
            c[i] = pack2(a, b);
        }
        // exchange quads across the h-halves (lane ^ 32) to build A-operand P frags
        u32 s0a = h ? c[0] : c[2], s0b = h ? c[1] : c[3];
        u32 s1a = h ? c[4] : c[6], s1b = h ? c[5] : c[7];
        u32 r0a = (u32)__shfl_xor((int)s0a, 32);
        u32 r0b = (u32)__shfl_xor((int)s0b, 32);
        u32 r1a = (u32)__shfl_xor((int)s1a, 32);
        u32 r1b = (u32)__shfl_xor((int)s1b, 32);
        union { u32 w[4]; bf16x8 v; } p0u, p1u;
        if (h == 0) {
            p0u.w[0] = c[0]; p0u.w[1] = c[1]; p0u.w[2] = r0a; p0u.w[3] = r0b;
            p1u.w[0] = c[4]; p1u.w[1] = c[5]; p1u.w[2] = r1a; p1u.w[3] = r1b;
        } else {
            p0u.w[0] = r0a; p0u.w[1] = r0b; p0u.w[2] = c[2]; p0u.w[3] = c[3];
            p1u.w[0] = r1a; p1u.w[1] = r1b; p1u.w[2] = c[6]; p1u.w[3] = c[7];
        }
        bf16x8 pf0 = p0u.v, pf1 = p1u.v;

        // delta_state via MFMA: B = state broadcast across all n columns
        const u16* stp = stb + mt * 32;
        bf16x8 st0 = *(const bf16x8*)(stp);
        bf16x8 st1 = *(const bf16x8*)(stp + 16);
        dsa = __builtin_amdgcn_mfma_f32_32x32x16_bf16(pf0, st0, dsa, 0, 0, 0);
        dsa = __builtin_amdgcn_mfma_f32_32x32x16_bf16(pf1, st1, dsa, 0, 0, 0);

        // O += P x Vt over all 256 e-columns
        const u16* vb = vbase0 + mt * 32;
        #pragma unroll
        for (int et = 0; et < 8; et++) {
            bf16x8 v0 = *(const bf16x8*)(vb + (size_t)et * 32 * 4096);
            bf16x8 v1 = *(const bf16x8*)(vb + (size_t)et * 32 * 4096 + 16);
            oacc[et] = __builtin_amdgcn_mfma_f32_32x32x16_bf16(pf0, v0, oacc[et], 0, 0, 0);
            oacc[et] = __builtin_amdgcn_mfma_f32_32x32x16_bf16(pf1, v1, oacc[et], 0, 0, 0);
        }
    }

    // ---- epilogue: reduce 4 msplit partials across waves via LDS ----
    float* myred = red + (wave & 1) * 8192;
    if (wave >= 2) {
        #pragma unroll
        for (int et = 0; et < 8; et++)
            #pragma unroll
            for (int r = 0; r < 16; r++)
                myred[((r & 3) + 8 * (r >> 2) + 4 * h) * 256 + et * 32 + l31] = oacc[et][r];
    }
    __syncthreads();
    if (l31 == 0) {
        #pragma unroll
        for (int r = 0; r < 16; r++)
            atomicAdd(&dsbuf[(r & 3) + 8 * (r >> 2) + 4 * h], dsa[r]);
    }
    if (wave < 2) {
        #pragma unroll
        for (int et = 0; et < 8; et++)
            #pragma unroll
            for (int r = 0; r < 16; r++)
                oacc[et][r] += myred[((r & 3) + 8 * (r >> 2) + 4 * h) * 256 + et * 32 + l31];
    }
    __syncthreads();
    if (wave == 1) {
        #pragma unroll
        for (int et = 0; et < 8; et++)
            #pragma unroll
            for (int r = 0; r < 16; r++)
                red[((r & 3) + 8 * (r >> 2) + 4 * h) * 256 + et * 32 + l31] = oacc[et][r];
    }
    __syncthreads();
    if (wave == 0) {
        #pragma unroll
        for (int et = 0; et < 8; et++)
            #pragma unroll
            for (int r = 0; r < 16; r++) {
                int row = (r & 3) + 8 * (r >> 2) + 4 * h;
                float v = oacc[et][r] + red[row * 256 + et * 32 + l31];
                dval_out[((size_t)(bb * 4096 + q0 + row)) * 256 + et * 32 + l31] = v;
            }
    }
    if (tid < 32) ds_out[bb * 4096 + q0 + tid] = dsbuf[tid];
}

extern "C" void kernel_launch(void* const* d_in, const int* in_sizes, int n_in,
                              void* d_out, int out_size, void* d_ws, size_t ws_size,
                              hipStream_t stream) {
    const float* val   = (const float*)d_in[0];   // [B,N,D] f32
    const float* state = (const float*)d_in[1];   // [B,N]   f32
    const float* Wv    = (const float*)d_in[2];   // [D,D]   f32

    float* ds_out   = (float*)d_out;              // [B,N]
    float* dval_out = ds_out + NB * NN;           // [B,N,D]

    u16* val_bf = (u16*)d_ws;                               // 8 MB
    u16* vT_bf  = val_bf + (size_t)NB * NN * ND;            // 8 MB
    u16* wvT    = vT_bf  + (size_t)NB * NN * ND;            // 128 KB
    u16* st_bf  = wvT + ND * ND;                            // 32 KB

    k_prep<<<4416, 256, 0, stream>>>(val, state, Wv, val_bf, wvT, st_bf);
    k_pv<<<1024, 64, 0, stream>>>(val_bf, wvT, vT_bf);
    k_main<<<512, 256, 0, stream>>>(val_bf, vT_bf, st_bf, ds_out, dval_out);
}

// Round 3
// 203.013 us; speedup vs baseline: 2.1878x; 1.7039x over previous
//
#include <hip/hip_runtime.h>

typedef unsigned short u16;
typedef unsigned int u32;
typedef __bf16 bf16x8 __attribute__((ext_vector_type(8)));
typedef float  f32x16 __attribute__((ext_vector_type(16)));

#define NB 4
#define NN 4096
#define ND 256

__device__ __forceinline__ u16 f2bf(float x) { return __builtin_bit_cast(u16, (__bf16)x); }
__device__ __forceinline__ float bf2f(u16 x) { u32 u = (u32)x << 16; return __builtin_bit_cast(float, u); }
__device__ __forceinline__ u32 pack2(float a, float b) { return (u32)f2bf(a) | ((u32)f2bf(b) << 16); }

typedef __attribute__((address_space(1))) const u32 gas_u32;
typedef __attribute__((address_space(3))) u32 las_u32;
__device__ __forceinline__ void async_ld16(void* lds, const void* g) {
    __builtin_amdgcn_global_load_lds((gas_u32*)g, (las_u32*)lds, 16, 0, 0);
}

// ws layout (u16* base):
//  kq  : [b][strip128][s16][lane64][8]   bf16, 8 MB   (A/B-operand frags of val)
//  vp  : [b][mt128][et8][seg2][lane64][8] bf16, 8 MB  (B-operand frags of (val@Wv)^T)
//  wv  : [es8][s16][lane64][8]           bf16, 128 KB (A-operand frags of Wv^T)
//  st  : [b*4096+n]                      bf16, 32 KB
//  part: [(b*4096+q)*256+e]              bf16, 8 MB   (msG=1 dval partial)
//  dsp : [b*4096+q]                      f32, 64 KB   (msG=1 ds partial)

// ---- pack val into fragment order (coalesced read via LDS tile) ----
__global__ __launch_bounds__(256) void k_pack_val(const float* __restrict__ val, u16* __restrict__ kq) {
    __shared__ float t[32 * 257];
    int bs = blockIdx.x;                       // b*128 + strip
    int tid = threadIdx.x;
    const float* src = val + (size_t)bs * 32 * 256;
    #pragma unroll
    for (int k = 0; k < 8; k++) {
        int idx = tid + k * 256;               // 2048 float4
        int row = idx >> 6, c4 = idx & 63;
        float4 v = *(const float4*)(src + row * 256 + c4 * 4);
        float* p = t + row * 257 + c4 * 4;
        p[0] = v.x; p[1] = v.y; p[2] = v.z; p[3] = v.w;
    }
    __syncthreads();
    u16* dst = kq + (size_t)bs * 16 * 512;
    #pragma unroll
    for (int k = 0; k < 4; k++) {
        int flat = tid + k * 256;              // [0,1024): s*64+lane
        int s = flat >> 6, l = flat & 63;
        int l31 = l & 31, h = l >> 5;
        const float* p = t + l31 * 257 + s * 16 + h * 8;
        union { u16 o[8]; uint4 q; } u;
        #pragma unroll
        for (int j = 0; j < 8; j++) u.o[j] = f2bf(p[j]);
        *(uint4*)(dst + (size_t)flat * 8) = u.q;
    }
}

// ---- pack Wv^T frags (blocks 0..7) + state bf16 (blocks 8..71) ----
__global__ __launch_bounds__(256) void k_pack_wv_state(const float* __restrict__ Wv,
                                                       const float* __restrict__ state,
                                                       u16* __restrict__ wv, u16* __restrict__ st) {
    int tid = threadIdx.x;
    if (blockIdx.x >= 8) {
        int i = (blockIdx.x - 8) * 256 + tid;
        st[i] = f2bf(state[i]);
        return;
    }
    __shared__ u16 t2[256 * 33];
    int es = blockIdx.x, e0 = es * 32;
    #pragma unroll
    for (int k = 0; k < 8; k++) {
        int idx = tid + k * 256;               // 2048: row(256) x c4(8)
        int row = idx >> 3, c4 = idx & 7;
        float4 v = *(const float4*)(Wv + row * 256 + e0 + c4 * 4);
        u16* p = t2 + row * 33 + c4 * 4;
        p[0] = f2bf(v.x); p[1] = f2bf(v.y); p[2] = f2bf(v.z); p[3] = f2bf(v.w);
    }
    __syncthreads();
    u16* dst = wv + (size_t)es * 16 * 512;
    #pragma unroll
    for (int k = 0; k < 4; k++) {
        int flat = tid + k * 256;
        int s = flat >> 6, l = flat & 63;
        int l31 = l & 31, h = l >> 5;
        union { u16 o[8]; uint4 q; } u;
        #pragma unroll
        for (int j = 0; j < 8; j++) u.o[j] = t2[(s * 16 + h * 8 + j) * 33 + l31];
        *(uint4*)(dst + (size_t)flat * 8) = u.q;
    }
}

// ---- pv^T = Wv^T x val^T, emitted directly in B-operand fragment order ----
__global__ __launch_bounds__(64) void k_pv(const u16* __restrict__ kq, const u16* __restrict__ wv,
                                           u16* __restrict__ vp) {
    __shared__ u16 tp[32 * 40];
    int wid = blockIdx.x;                      // 1024
    int lane = threadIdx.x;
    int l31 = lane & 31, h = lane >> 5;
    int bb = wid >> 8, es = (wid >> 5) & 7, qb = wid & 31;
    const u16* wvb = wv + (size_t)(es * 16) * 512 + lane * 8;
    const u16* kqb = kq + ((size_t)(bb * 128 + qb * 4) * 16) * 512 + lane * 8;
    f32x16 acc[4] = {};
    for (int s = 0; s < 16; s++) {
        bf16x8 af = *(const bf16x8*)(wvb + s * 512);
        #pragma unroll
        for (int qt = 0; qt < 4; qt++) {
            bf16x8 bfr = *(const bf16x8*)(kqb + (size_t)(qt * 16 + s) * 512);
            acc[qt] = __builtin_amdgcn_mfma_f32_32x32x16_bf16(af, bfr, acc[qt], 0, 0, 0);
        }
    }
    #pragma unroll
    for (int qt = 0; qt < 4; qt++) {
        #pragma unroll
        for (int r = 0; r < 16; r++) {
            int erow = (r & 3) + 8 * (r >> 2) + 4 * h;
            tp[erow * 40 + l31] = f2bf(acc[qt][r]);
        }
        __syncthreads();
        #pragma unroll
        for (int seg = 0; seg < 2; seg++) {
            uint4 v = *(const uint4*)(tp + l31 * 40 + seg * 16 + h * 8);
            *(uint4*)(vp + (((size_t)(bb * 128 + qb * 4 + qt) * 16) + es * 2 + seg) * 512 + lane * 8) = v;
        }
        __syncthreads();
    }
}

// ---- main: LDS-staged flash softsign, dbuf, 1 barrier/64m tile ----
__global__ __launch_bounds__(512, 2) void k_main(const u16* __restrict__ kq,
                                                 const u16* __restrict__ vp,
                                                 const u16* __restrict__ st,
                                                 u16* __restrict__ part, float* __restrict__ dsp,
                                                 float* __restrict__ ds_out, float* __restrict__ dval_out) {
    __shared__ u16 stage[2 * 32768];           // 128 KB: per buf [K ms0|K ms1|V ms0|V ms1] x 16KB
    __shared__ float dsred[4][32];

    int tid = threadIdx.x;
    int w = tid >> 6, lane = tid & 63;
    int l31 = lane & 31, h = lane >> 5;
    int s4 = w & 3, msL = w >> 2;

    int id = blockIdx.x;
    int xcd = id & 7;
    int bb = xcd >> 1;
    int t6 = ((xcd & 1) << 5) | (id >> 3);     // [0,64)
    int qb = t6 >> 1, msG = t6 & 1;
    int q0 = qb * 128;
    int m_base = msG * 2048;

    // Q fragments resident (strip = qb*4 + s4)
    const u16* qsrc = kq + ((size_t)(bb * 128 + qb * 4 + s4) * 16) * 512 + lane * 8;
    bf16x8 qf[16];
    #pragma unroll
    for (int s = 0; s < 16; s++) qf[s] = *(const bf16x8*)(qsrc + (size_t)s * 512);

    f32x16 oacc[8] = {};
    f32x16 dsa = {};

    // stage tile 0
    {
        int mstrip0 = (m_base >> 5);
        const u16* srcK = kq + ((size_t)(bb * 128 + mstrip0) * 16) * 512;
        const u16* srcV = vp + ((size_t)(bb * 128 + mstrip0) * 16) * 512;
        #pragma unroll
        for (int k = 0; k < 8; k++) {
            int cb = w * 64 + k * 512;
            int c = cb + lane;
            const u16* s = (cb < 2048 * 1 ? srcK : srcV) + (size_t)(c & 2047) * 8;
            async_ld16(stage + (size_t)cb * 8, s);
        }
    }
    __syncthreads();

    for (int mt = 0; mt < 32; mt++) {
        int buf = mt & 1;
        u16* stageb = stage + buf * 32768;
        // issue next stage into other buffer
        if (mt + 1 < 32) {
            int mstrip0 = ((m_base + (mt + 1) * 64) >> 5);
            const u16* srcK = kq + ((size_t)(bb * 128 + mstrip0) * 16) * 512;
            const u16* srcV = vp + ((size_t)(bb * 128 + mstrip0) * 16) * 512;
            u16* dstb = stage + (buf ^ 1) * 32768;
            #pragma unroll
            for (int k = 0; k < 8; k++) {
                int cb = w * 64 + k * 512;
                int c = cb + lane;
                const u16* s = (cb < 2048 ? srcK : srcV) + (size_t)(c & 2047) * 8;
                async_ld16(dstb + (size_t)cb * 8, s);
            }
        }

        // S^T = K x Q^T
        const u16* kbuf = stageb + msL * 8192;
        f32x16 sacc = {};
        #pragma unroll
        for (int s = 0; s < 16; s++) {
            bf16x8 kf = *(const bf16x8*)(kbuf + (s * 64 + lane) * 8);
            sacc = __builtin_amdgcn_mfma_f32_32x32x16_bf16(kf, qf[s], sacc, 0, 0, 0);
        }
        // softsign + pack
        u32 c[8];
        #pragma unroll
        for (int i = 0; i < 8; i++) {
            float a = sacc[2 * i], b = sacc[2 * i + 1];
            a = a / (1.0f + fabsf(a));
            b = b / (1.0f + fabsf(b));
            c[i] = pack2(a, b);
        }
        u32 s0a = h ? c[0] : c[2], s0b = h ? c[1] : c[3];
        u32 s1a = h ? c[4] : c[6], s1b = h ? c[5] : c[7];
        u32 r0a = (u32)__shfl_xor((int)s0a, 32);
        u32 r0b = (u32)__shfl_xor((int)s0b, 32);
        u32 r1a = (u32)__shfl_xor((int)s1a, 32);
        u32 r1b = (u32)__shfl_xor((int)s1b, 32);
        union { u32 wd[4]; bf16x8 v; } p0u, p1u;
        if (h == 0) {
            p0u.wd[0] = c[0]; p0u.wd[1] = c[1]; p0u.wd[2] = r0a; p0u.wd[3] = r0b;
            p1u.wd[0] = c[4]; p1u.wd[1] = c[5]; p1u.wd[2] = r1a; p1u.wd[3] = r1b;
        } else {
            p0u.wd[0] = r0a; p0u.wd[1] = r0b; p0u.wd[2] = c[2]; p0u.wd[3] = c[3];
            p1u.wd[0] = r1a; p1u.wd[1] = r1b; p1u.wd[2] = c[6]; p1u.wd[3] = c[7];
        }
        bf16x8 pf0 = p0u.v, pf1 = p1u.v;

        // delta_state MFMA (state broadcast in B)
        const u16* stp = st + bb * 4096 + m_base + mt * 64 + msL * 32 + h * 8;
        bf16x8 st0 = *(const bf16x8*)(stp);
        bf16x8 st1 = *(const bf16x8*)(stp + 16);
        dsa = __builtin_amdgcn_mfma_f32_32x32x16_bf16(pf0, st0, dsa, 0, 0, 0);
        dsa = __builtin_amdgcn_mfma_f32_32x32x16_bf16(pf1, st1, dsa, 0, 0, 0);

        // O += P x Vt
        const u16* vbuf = stageb + 16384 + msL * 8192;
        #pragma unroll
        for (int et = 0; et < 8; et++) {
            bf16x8 v0 = *(const bf16x8*)(vbuf + ((et * 2 + 0) * 64 + lane) * 8);
            bf16x8 v1 = *(const bf16x8*)(vbuf + ((et * 2 + 1) * 64 + lane) * 8);
            oacc[et] = __builtin_amdgcn_mfma_f32_32x32x16_bf16(pf0, v0, oacc[et], 0, 0, 0);
            oacc[et] = __builtin_amdgcn_mfma_f32_32x32x16_bf16(pf1, v1, oacc[et], 0, 0, 0);
        }
        __syncthreads();   // drains async stage + protects buffers; ONE barrier per tile
    }

    // ---- epilogue: combine msL pairs via LDS (stage reused as f32 scratch) ----
    float* redf = (float*)stage;               // 4 strips x 32 q x 256 e = 128 KB
    if (msL == 1) {
        #pragma unroll
        for (int et = 0; et < 8; et++)
            #pragma unroll
            for (int r = 0; r < 16; r++) {
                int row = (r & 3) + 8 * (r >> 2) + 4 * h;
                redf[(s4 * 32 + row) * 256 + et * 32 + l31] = oacc[et][r];
            }
        if (l31 == 0) {
            #pragma unroll
            for (int r = 0; r < 16; r++) {
                int row = (r & 3) + 8 * (r >> 2) + 4 * h;
                dsred[s4][row] = dsa[r];
            }
        }
    }
    __syncthreads();
    if (msL == 0) {
        #pragma unroll
        for (int et = 0; et < 8; et++)
            #pragma unroll
            for (int r = 0; r < 16; r++) {
                int row = (r & 3) + 8 * (r >> 2) + 4 * h;
                float v = oacc[et][r] + redf[(s4 * 32 + row) * 256 + et * 32 + l31];
                size_t oidx = ((size_t)(bb * 4096 + q0 + s4 * 32 + row)) * 256 + et * 32 + l31;
                if (msG == 0) dval_out[oidx] = v;
                else part[oidx] = f2bf(v);
            }
        if (l31 == 0) {
            #pragma unroll
            for (int r = 0; r < 16; r++) {
                int row = (r & 3) + 8 * (r >> 2) + 4 * h;
                float v = dsa[r] + dsred[s4][row];
                int qi = bb * 4096 + q0 + s4 * 32 + row;
                if (msG == 0) ds_out[qi] = v;
                else dsp[qi] = v;
            }
        }
    }
}

// ---- combine msG=1 partials into outputs ----
__global__ __launch_bounds__(256) void k_combine(const u16* __restrict__ part, const float* __restrict__ dsp,
                                                 float* __restrict__ ds_out, float* __restrict__ dval_out) {
    int b = blockIdx.x;
    if (b < 4096) {
        int i = b * 256 + threadIdx.x;         // float4 over 4M dval
        float4 d = ((const float4*)dval_out)[i];
        ushort4 p = ((const ushort4*)part)[i];
        d.x += bf2f(p.x); d.y += bf2f(p.y); d.z += bf2f(p.z); d.w += bf2f(p.w);
        ((float4*)dval_out)[i] = d;
    } else {
        int k = (b - 4096) * 256 + threadIdx.x;
        ds_out[k] += dsp[k];
    }
}

extern "C" void kernel_launch(void* const* d_in, const int* in_sizes, int n_in,
                              void* d_out, int out_size, void* d_ws, size_t ws_size,
                              hipStream_t stream) {
    const float* val   = (const float*)d_in[0];
    const float* state = (const float*)d_in[1];
    const float* Wv    = (const float*)d_in[2];

    float* ds_out   = (float*)d_out;
    float* dval_out = ds_out + NB * NN;

    u16* kq  = (u16*)d_ws;                                  // 8 MB
    u16* vp  = kq + (size_t)NB * NN * ND;                   // 8 MB
    u16* wv  = vp + (size_t)NB * NN * ND;                   // 128 KB
    u16* st  = wv + 8 * 16 * 512;                           // 32 KB
    u16* part = st + NB * NN;                               // 8 MB
    float* dsp = (float*)(part + (size_t)NB * NN * ND);     // 64 KB

    k_pack_val<<<NB * NN / 32, 256, 0, stream>>>(val, kq);
    k_pack_wv_state<<<72, 256, 0, stream>>>(Wv, state, wv, st);
    k_pv<<<1024, 64, 0, stream>>>(kq, wv, vp);
    k_main<<<256, 512, 0, stream>>>(kq, vp, st, part, dsp, ds_out, dval_out);
    k_combine<<<4096 + 64, 256, 0, stream>>>(part, dsp, ds_out, dval_out);
}